// Round 2
// baseline (61.480 us; speedup 1.0000x reference)
//
#include <hip/hip_runtime.h>
#include <math.h>

#define NB 16
#define NS 2048
#define NE 8
#define NH 2
#define ND 4
#define NF 512
#define QPB 128
#define NSPLIT 4
#define NTHREADS 1024
#define LNEPS 1e-5f

#if defined(__has_builtin)
# if __has_builtin(__builtin_amdgcn_exp2f)
#  define EXP2(x) __builtin_amdgcn_exp2f(x)
# else
#  define EXP2(x) exp2f(x)
# endif
#else
# define EXP2(x) exp2f(x)
#endif

__global__ __launch_bounds__(NTHREADS)
void qtb_kernel(const float* __restrict__ x,
                const float* __restrict__ theta_rx,
                const float* __restrict__ w_out,
                const float* __restrict__ theta_ry,
                const float* __restrict__ w1,
                const float* __restrict__ b1,
                const float* __restrict__ w2,
                const float* __restrict__ b2,
                const float* __restrict__ g1,
                const float* __restrict__ be1,
                const float* __restrict__ g2,
                const float* __restrict__ be2,
                float* __restrict__ out)
{
    __shared__ float z_s[NS][NE];                 // 64 KB: z for the whole (b, :) sequence
    __shared__ float w1_s[NF][NE];                // 16 KB
    __shared__ float w2t_s[NF][NE];               // 16 KB (transposed: w2t[f][e] = w2[e][f])
    __shared__ float part_s[QPB][NH][NSPLIT][6];  // 24 KB partial softmax sums
    __shared__ float attn_s[QPB][NE + 1];         // 4.5 KB (padded stride 9)
    __shared__ float wout_s[NE][NE];
    __shared__ float b1_s[NF];
    __shared__ float th_s[NE], cry_s[NE], g1_s[NE], be1_s[NE], g2_s[NE], be2_s[NE], b2_s[NE];

    const int t = threadIdx.x;
    const int bid = blockIdx.x;
    const int b = bid >> 4;        // 16 batches
    const int chunk = bid & 15;    // 16 query-chunks of 128

    // ---- phase 0: stage weights ----
    for (int i = t; i < NF * NE; i += NTHREADS) {
        ((float*)w1_s)[i] = w1[i];                // w1 is (F,E) row-major == w1_s layout
        const int e = i >> 9, f = i & (NF - 1);   // i = e*512 + f for w2 (E,F)
        w2t_s[f][e] = w2[i];
    }
    if (t < NE * NE) ((float*)wout_s)[t] = w_out[t];
    if (t < NF) b1_s[t] = b1[t];
    if (t < NE) {
        th_s[t]  = theta_rx[t];
        cry_s[t] = __cosf(theta_ry[t]);
        g1_s[t]  = g1[t];  be1_s[t] = be1[t];
        g2_s[t]  = g2[t];  be2_s[t] = be2[t];
        b2_s[t]  = b2[t];
    }
    __syncthreads();   // th_s (and weights) must be visible to ALL waves before phase 1

    const float* xb = x + (size_t)b * NS * NE;

    // ---- phase 1: quantum head z for all 2048 rows of this batch ----
    for (int r = t; r < NS; r += NTHREADS) {
        const float4 v0 = *reinterpret_cast<const float4*>(xb + r * NE);
        const float4 v1 = *reinterpret_cast<const float4*>(xb + r * NE + 4);
        const float c0 = __cosf(v0.x + th_s[0]);
        const float c1 = __cosf(v0.y + th_s[1]);
        const float c2 = __cosf(v0.z + th_s[2]);
        const float c3 = __cosf(v0.w + th_s[3]);
        const float c4 = __cosf(v1.x + th_s[4]);
        const float c5 = __cosf(v1.y + th_s[5]);
        const float c6 = __cosf(v1.z + th_s[6]);
        const float c7 = __cosf(v1.w + th_s[7]);
        const float p1 = c0 * c1, p2 = p1 * c2, p3 = p2 * c3, p4 = p3 * c4;
        const float p5 = p4 * c5, p6 = p5 * c6, p7 = p6 * c7;
        // z0 = c1*c2*...*c7 (suffix product, avoid division by c0)
        const float s6 = c7 * c6, s5 = s6 * c5, s4 = s5 * c4;
        const float s3 = s4 * c3, s2 = s3 * c2, z0 = s2 * c1;
        float4 a0; a0.x = z0; a0.y = p1; a0.z = p2; a0.w = p3;
        float4 a1; a1.x = p4; a1.y = p5; a1.z = p6; a1.w = p7;
        *reinterpret_cast<float4*>(&z_s[r][0]) = a0;
        *reinterpret_cast<float4*>(&z_s[r][4]) = a1;
    }
    __syncthreads();

    // ---- phase 2: attention, single-pass softmax (|scores|<=2, no max needed) ----
    {
        const int split = t >> 8;          // 0..3 : key-range split
        const int rem = t & 255;
        const int h = rem >> 7;            // head
        const int r = rem & 127;           // query within chunk
        const int q = chunk * QPB + r;
        const float SC = 0.7213475204444817f;  // log2(e) / sqrt(D)=2
        const float q0 = z_s[q][h * 4 + 0] * SC;
        const float q1 = z_s[q][h * 4 + 1] * SC;
        const float q2 = z_s[q][h * 4 + 2] * SC;
        const float q3 = z_s[q][h * 4 + 3] * SC;
        float o0 = 0.f, o1 = 0.f, o2 = 0.f, o3 = 0.f, den = 0.f;
        const int j0 = split * (NS / NSPLIT);
        #pragma unroll 8
        for (int j = j0; j < j0 + NS / NSPLIT; ++j) {
            const float4 k = *reinterpret_cast<const float4*>(&z_s[j][h * 4]);  // wave-uniform -> LDS broadcast
            const float s = q0 * k.x + q1 * k.y + q2 * k.z + q3 * k.w;
            const float e = EXP2(s);
            den += e;
            o0 += e * k.x; o1 += e * k.y; o2 += e * k.z; o3 += e * k.w;
        }
        part_s[r][h][split][0] = o0; part_s[r][h][split][1] = o1;
        part_s[r][h][split][2] = o2; part_s[r][h][split][3] = o3;
        part_s[r][h][split][4] = den;
    }
    __syncthreads();

    // ---- phase 3: combine key-splits ----
    if (t < QPB * NH) {
        const int h = t >> 7, r = t & 127;
        float o0 = 0.f, o1 = 0.f, o2 = 0.f, o3 = 0.f, den = 0.f;
        #pragma unroll
        for (int sp = 0; sp < NSPLIT; ++sp) {
            o0 += part_s[r][h][sp][0]; o1 += part_s[r][h][sp][1];
            o2 += part_s[r][h][sp][2]; o3 += part_s[r][h][sp][3];
            den += part_s[r][h][sp][4];
        }
        const float inv = 1.0f / den;
        attn_s[r][h * 4 + 0] = o0 * inv; attn_s[r][h * 4 + 1] = o1 * inv;
        attn_s[r][h * 4 + 2] = o2 * inv; attn_s[r][h * 4 + 3] = o3 * inv;
    }
    __syncthreads();

    // ---- phase 4: fused epilogue: out_proj -> LN1 -> quantum FFN -> LN2 ----
    {
        const int r = t >> 3;          // row within chunk (0..127)
        const int sub = t & 7;         // F-split (8 threads/row)
        const int q = chunk * QPB + r;

        float a[NE];
        #pragma unroll
        for (int e = 0; e < NE; ++e) a[e] = attn_s[r][e];

        float y[NE];
        #pragma unroll
        for (int e = 0; e < NE; ++e) {
            float acc = 0.f;
            #pragma unroll
            for (int k = 0; k < NE; ++k) acc += a[k] * wout_s[e][k];
            y[e] = acc;
        }

        const float4 xv0 = *reinterpret_cast<const float4*>(xb + q * NE);
        const float4 xv1 = *reinterpret_cast<const float4*>(xb + q * NE + 4);
        float t1[NE];
        t1[0] = xv0.x + y[0]; t1[1] = xv0.y + y[1]; t1[2] = xv0.z + y[2]; t1[3] = xv0.w + y[3];
        t1[4] = xv1.x + y[4]; t1[5] = xv1.y + y[5]; t1[6] = xv1.z + y[6]; t1[7] = xv1.w + y[7];

        float mu = 0.f;
        #pragma unroll
        for (int e = 0; e < NE; ++e) mu += t1[e];
        mu *= 0.125f;
        float var = 0.f;
        #pragma unroll
        for (int e = 0; e < NE; ++e) { const float d = t1[e] - mu; var += d * d; }
        var *= 0.125f;
        const float inv1 = rsqrtf(var + LNEPS);
        float x1v[NE];
        #pragma unroll
        for (int e = 0; e < NE; ++e) x1v[e] = (t1[e] - mu) * inv1 * g1_s[e] + be1_s[e];

        float zf[NE];
        #pragma unroll
        for (int e = 0; e < NE; ++e) zf[e] = cry_s[e] * __cosf(x1v[e]);

        float acc[NE] = {0.f, 0.f, 0.f, 0.f, 0.f, 0.f, 0.f, 0.f};
        #pragma unroll 8
        for (int i = 0; i < NF / NE; ++i) {
            const int f = sub + (i << 3);  // interleaved -> 2-way LDS conflict max (free)
            const float4 wA = *reinterpret_cast<const float4*>(&w1_s[f][0]);
            const float4 wB = *reinterpret_cast<const float4*>(&w1_s[f][4]);
            float hv = b1_s[f] + zf[0] * wA.x + zf[1] * wA.y + zf[2] * wA.z + zf[3] * wA.w
                               + zf[4] * wB.x + zf[5] * wB.y + zf[6] * wB.z + zf[7] * wB.w;
            hv = fmaxf(hv, 0.f);
            const float4 uA = *reinterpret_cast<const float4*>(&w2t_s[f][0]);
            const float4 uB = *reinterpret_cast<const float4*>(&w2t_s[f][4]);
            acc[0] += hv * uA.x; acc[1] += hv * uA.y; acc[2] += hv * uA.z; acc[3] += hv * uA.w;
            acc[4] += hv * uB.x; acc[5] += hv * uB.y; acc[6] += hv * uB.z; acc[7] += hv * uB.w;
        }

        // butterfly reduce over the 8 sub-lanes (consecutive lanes in-wave)
        #pragma unroll
        for (int m = 1; m < 8; m <<= 1) {
            #pragma unroll
            for (int e = 0; e < NE; ++e) acc[e] += __shfl_xor(acc[e], m, 64);
        }

        float t2[NE];
        #pragma unroll
        for (int e = 0; e < NE; ++e) t2[e] = x1v[e] + acc[e] + b2_s[e];
        float mu2 = 0.f;
        #pragma unroll
        for (int e = 0; e < NE; ++e) mu2 += t2[e];
        mu2 *= 0.125f;
        float var2 = 0.f;
        #pragma unroll
        for (int e = 0; e < NE; ++e) { const float d = t2[e] - mu2; var2 += d * d; }
        var2 *= 0.125f;
        const float inv2 = rsqrtf(var2 + LNEPS);

        // each of the 8 sub-lanes writes one element -> fully coalesced
        out[((size_t)b * NS + q) * NE + sub] = (t2[sub] - mu2) * inv2 * g2_s[sub] + be2_s[sub];
    }
}

extern "C" void kernel_launch(void* const* d_in, const int* in_sizes, int n_in,
                              void* d_out, int out_size, void* d_ws, size_t ws_size,
                              hipStream_t stream) {
    const float* x        = (const float*)d_in[0];
    const float* theta_rx = (const float*)d_in[1];
    const float* w_out    = (const float*)d_in[2];
    const float* theta_ry = (const float*)d_in[3];
    const float* w1       = (const float*)d_in[4];
    const float* b1       = (const float*)d_in[5];
    const float* w2       = (const float*)d_in[6];
    const float* b2       = (const float*)d_in[7];
    const float* g1       = (const float*)d_in[8];
    const float* be1      = (const float*)d_in[9];
    const float* g2       = (const float*)d_in[10];
    const float* be2      = (const float*)d_in[11];
    float* out = (float*)d_out;

    dim3 grid(NB * (NS / QPB));   // 256 blocks = 1 per CU
    dim3 block(NTHREADS);
    qtb_kernel<<<grid, block, 0, stream>>>(x, theta_rx, w_out, theta_ry,
                                           w1, b1, w2, b2, g1, be1, g2, be2, out);
}

// Round 3
// 40.184 us; speedup vs baseline: 1.5300x; 1.5300x over previous
//
#include <hip/hip_runtime.h>
#include <math.h>

#define NB 16
#define NS 2048
#define NE 8
#define NH 2
#define NF 512
#define DEG 6
#define NMONO 210          // #monomials in 4 vars, total degree <= 6
#define PHI_LD 66          // fp16 row stride (64 keys + 2 pad)
#define QPB 128
#define LNEPS 1e-5f

typedef float f32x2 __attribute__((ext_vector_type(2)));

// Power-basis coefficients of degree-6 truncated Chebyshev approx of e^x on
// [-2,2], in t = x/2:  e^x ~= sum_p ACOEF[p] * t^p.  Max abs err ~5e-4
// (verified at x = -2, 0, 1, 2: errors +4.0e-4, -5.5e-5, -1.9e-4, -5.1e-4).
__device__ const float ACOEF[8] = {0.99994459f, 2.00308514f, 2.00174650f,
                                   1.30890404f, 0.65803033f, 0.31441604f,
                                   0.10241921f, 0.0f};

// ws layout (floats):
//   PART:  [bh(32)][kc(32)][NMONO][5]   per-chunk partial moments
//   MNUM:  [bh(32)][NMONO][4]           reduced, w-folded numerator moments
//   MDEN:  [bh(32)][NMONO]              reduced denominator moments
#define PART_OFF 0
#define PART_SZ  (32*32*(NMONO*5))
#define MNUM_OFF PART_SZ
#define MNUM_SZ  (32*NMONO*4)
#define MDEN_OFF (MNUM_OFF + MNUM_SZ)

// ---------------- K1: per-64-key-chunk partial moments ----------------
__global__ __launch_bounds__(256)
void k1_moments(const float* __restrict__ x, const float* __restrict__ theta_rx,
                float* __restrict__ ws) {
    __shared__ _Float16 Phi[NMONO * PHI_LD];   // w-folded monomials, fp16
    __shared__ float4 klds[64];                // head-dims per key
    __shared__ float A_s[8], inv_s[8], th_s[8];

    const int t = threadIdx.x, bid = blockIdx.x;
    const int kc = bid & 31, h = (bid >> 5) & 1, b = bid >> 6;

    if (t < 8) {
        A_s[t]   = ACOEF[t];
        inv_s[t] = (t == 0) ? 1.f : 1.f / (float)t;
        th_s[t]  = theta_rx[t];
    }
    __syncthreads();

    if (t < 64) {
        const float* xr = x + ((size_t)b * NS + kc * 64 + t) * NE;
        const float4 v0 = *reinterpret_cast<const float4*>(xr);
        const float4 v1 = *reinterpret_cast<const float4*>(xr + 4);
        const float c0 = __cosf(v0.x + th_s[0]), c1 = __cosf(v0.y + th_s[1]);
        const float c2 = __cosf(v0.z + th_s[2]), c3 = __cosf(v0.w + th_s[3]);
        const float c4 = __cosf(v1.x + th_s[4]), c5 = __cosf(v1.y + th_s[5]);
        const float c6 = __cosf(v1.z + th_s[6]), c7 = __cosf(v1.w + th_s[7]);
        const float p1 = c0*c1, p2 = p1*c2, p3 = p2*c3, p4 = p3*c4;
        const float p5 = p4*c5, p6 = p5*c6, p7 = p6*c7;
        float k0, k1v, k2v, k3v;
        if (h == 0) {
            const float s6 = c7*c6, s5 = s6*c5, s4 = s5*c4, s3 = s4*c3, s2 = s3*c2;
            k0 = s2*c1; k1v = p1; k2v = p2; k3v = p3;
        } else {
            k0 = p4; k1v = p5; k2v = p6; k3v = p7;
        }
        klds[t] = make_float4(k0, k1v, k2v, k3v);

        // build w_alpha * k^alpha for all 210 monomials (this key = lane t).
        // M-levels maintain the multinomial p!/(a0!a1!a2!a3!) incrementally.
        int idx = 0;
        float M0 = 1.f, P0 = 1.f;
        for (int q0 = 0; q0 <= DEG; ++q0) {
            float M1 = M0, P1 = P0;
            for (int q1 = 0; q1 <= DEG - q0; ++q1) {
                float M2 = M1, P2 = P1;
                for (int q2 = 0; q2 <= DEG - q0 - q1; ++q2) {
                    float M3 = M2, P3 = P2;
                    for (int q3 = 0; q3 <= DEG - q0 - q1 - q2; ++q3) {
                        const float w = A_s[q0 + q1 + q2 + q3] * M3;
                        Phi[idx * PHI_LD + t] = (_Float16)(w * P3);
                        ++idx;
                        M3 *= (float)(q0 + q1 + q2 + q3 + 1) * inv_s[q3 + 1];
                        P3 *= k3v;
                    }
                    M2 *= (float)(q0 + q1 + q2 + 1) * inv_s[q2 + 1];
                    P2 *= k2v;
                }
                M1 *= (float)(q0 + q1 + 1) * inv_s[q1 + 1];
                P1 *= k1v;
            }
            M0 *= (float)(q0 + 1) * inv_s[q0 + 1];
            P0 *= k0;
        }
    }
    __syncthreads();

    if (t < NMONO) {   // feature-GEMM: one monomial per thread over 64 keys
        f32x2 a01 = {0.f, 0.f}, a23 = {0.f, 0.f};
        float a4 = 0.f;
        #pragma unroll 4
        for (int key = 0; key < 64; ++key) {
            const float phi = (float)Phi[t * PHI_LD + key];
            const float4 kv = klds[key];                 // wave-uniform
            const f32x2 w01 = {kv.x, kv.y}, w23 = {kv.z, kv.w};
            a01 += phi * w01;
            a23 += phi * w23;
            a4  += phi;
        }
        float* dst = ws + PART_OFF + (size_t)bid * (NMONO * 5) + t * 5;
        dst[0] = a01.x; dst[1] = a01.y; dst[2] = a23.x; dst[3] = a23.y; dst[4] = a4;
    }
}

// ---------------- K1.5: reduce 32 chunks -> final moments ----------------
__global__ __launch_bounds__(256)
void k15_reduce(float* __restrict__ ws) {
    const int t = threadIdx.x, bh = blockIdx.x;
    const float* src = ws + PART_OFF + (size_t)bh * 32 * (NMONO * 5);
    float* mnum = ws + MNUM_OFF + (size_t)bh * NMONO * 4;
    float* mden = ws + MDEN_OFF + (size_t)bh * NMONO;
    for (int i = t; i < NMONO * 5; i += 256) {
        float s = 0.f;
        for (int kc = 0; kc < 32; ++kc) s += src[(size_t)kc * (NMONO * 5) + i];
        const int al = i / 5, c = i - al * 5;
        if (c < 4) mnum[al * 4 + c] = s; else mden[al] = s;
    }
}

// ---------------- K2: queries + fused epilogue ----------------
__global__ __launch_bounds__(1024)
void k2_main(const float* __restrict__ x, const float* __restrict__ theta_rx,
             const float* __restrict__ w_out, const float* __restrict__ theta_ry,
             const float* __restrict__ w1, const float* __restrict__ b1,
             const float* __restrict__ w2, const float* __restrict__ b2,
             const float* __restrict__ g1, const float* __restrict__ be1,
             const float* __restrict__ g2, const float* __restrict__ be2,
             const float* __restrict__ ws, float* __restrict__ out) {
    __shared__ float4 Mn_lds[2 * NMONO];       // [h][alpha] numerator moments
    __shared__ float  Md_lds[2 * NMONO];       // [h][alpha] denominator
    __shared__ float  z_c[8][QPB];             // z columns
    __shared__ float  x1_c[8][QPB];
    __shared__ float  zf_c[8][QPB];            // later reused for t2
    __shared__ float  attn_c[8][QPB];
    __shared__ float  part_a[4][256][5];
    __shared__ float  part_f[8][8][QPB];       // [fsplit][e][row]
    __shared__ float  w1_s[NF][NE];
    __shared__ float  w2t_s[NF][NE];
    __shared__ float  b1_s[NF];
    __shared__ float  wout_s[NE][NE];
    __shared__ float  th_s[8], cry_s[8], g1_s[8], be1_s[8], g2_s[8], be2_s[8], b2_s[8];

    const int t = threadIdx.x, bid = blockIdx.x;
    const int b = bid >> 4, qc = bid & 15;

    // ---- stage ----
    for (int i = t; i < NF * NE; i += 1024) {
        ((float*)w1_s)[i] = w1[i];
        const int e = i >> 9, f = i & (NF - 1);
        w2t_s[f][e] = w2[i];
    }
    {
        const float* mn = ws + MNUM_OFF + (size_t)(b * 2) * NMONO * 4;
        for (int i = t; i < 2 * NMONO * 4; i += 1024) ((float*)Mn_lds)[i] = mn[i];
        const float* md = ws + MDEN_OFF + (size_t)(b * 2) * NMONO;
        for (int i = t; i < 2 * NMONO; i += 1024) Md_lds[i] = md[i];
    }
    if (t < NF) b1_s[t] = b1[t];
    if (t < NE * NE) ((float*)wout_s)[t] = w_out[t];
    if (t < 8) {
        th_s[t]  = theta_rx[t];
        cry_s[t] = __cosf(theta_ry[t]);
        g1_s[t]  = g1[t];  be1_s[t] = be1[t];
        g2_s[t]  = g2[t];  be2_s[t] = be2[t];
        b2_s[t]  = b2[t];
    }
    __syncthreads();

    // ---- P1: z for the 128 query rows ----
    if (t < QPB) {
        const float* xr = x + ((size_t)b * NS + qc * QPB + t) * NE;
        const float4 v0 = *reinterpret_cast<const float4*>(xr);
        const float4 v1 = *reinterpret_cast<const float4*>(xr + 4);
        const float c0 = __cosf(v0.x + th_s[0]), c1 = __cosf(v0.y + th_s[1]);
        const float c2 = __cosf(v0.z + th_s[2]), c3 = __cosf(v0.w + th_s[3]);
        const float c4 = __cosf(v1.x + th_s[4]), c5 = __cosf(v1.y + th_s[5]);
        const float c6 = __cosf(v1.z + th_s[6]), c7 = __cosf(v1.w + th_s[7]);
        const float p1 = c0*c1, p2 = p1*c2, p3 = p2*c3, p4 = p3*c4;
        const float p5 = p4*c5, p6 = p5*c6, p7 = p6*c7;
        const float s6 = c7*c6, s5 = s6*c5, s4 = s5*c4, s3 = s4*c3, s2 = s3*c2;
        z_c[0][t] = s2*c1; z_c[1][t] = p1; z_c[2][t] = p2; z_c[3][t] = p3;
        z_c[4][t] = p4;    z_c[5][t] = p5; z_c[6][t] = p6; z_c[7][t] = p7;
    }
    __syncthreads();

    // ---- P2: attention via monomial dot with moments (4 p0-groups) ----
    {
        const int g = t >> 8, u = t & 255, h = u >> 7, r = u & 127;
        int p0s, p0e, base;
        if (g == 0)      { p0s = 0; p0e = 0; base = 0;   }
        else if (g == 1) { p0s = 1; p0e = 1; base = 84;  }
        else if (g == 2) { p0s = 2; p0e = 3; base = 140; }
        else             { p0s = 4; p0e = 6; base = 195; }
        const float u0 = z_c[h*4+0][r] * 0.25f, u1 = z_c[h*4+1][r] * 0.25f;
        const float u2 = z_c[h*4+2][r] * 0.25f, u3 = z_c[h*4+3][r] * 0.25f;
        f32x2 a01 = {0.f, 0.f}, a23 = {0.f, 0.f};
        float ad = 0.f;
        float P0 = 1.f;
        for (int i = 0; i < p0s; ++i) P0 *= u0;
        int off = h * NMONO + base;
        for (int q0 = p0s; q0 <= p0e; ++q0) {
            float P1 = P0;
            for (int q1 = 0; q1 <= DEG - q0; ++q1) {
                float P2 = P1;
                for (int q2 = 0; q2 <= DEG - q0 - q1; ++q2) {
                    float P3 = P2;
                    for (int q3 = 0; q3 <= DEG - q0 - q1 - q2; ++q3) {
                        const float4 mv = Mn_lds[off];     // wave-uniform
                        const float  md = Md_lds[off];
                        const f32x2 m01 = {mv.x, mv.y}, m23 = {mv.z, mv.w};
                        a01 += P3 * m01;
                        a23 += P3 * m23;
                        ad  += P3 * md;
                        ++off;
                        P3 *= u3;
                    }
                    P2 *= u2;
                }
                P1 *= u1;
            }
            P0 *= u0;
        }
        float* pa = &part_a[g][u][0];
        pa[0] = a01.x; pa[1] = a01.y; pa[2] = a23.x; pa[3] = a23.y; pa[4] = ad;
    }
    __syncthreads();

    // ---- P3: combine monomial groups, normalize ----
    if (t < 256) {
        const int h = t >> 7, r = t & 127;
        float n0 = 0.f, n1 = 0.f, n2 = 0.f, n3 = 0.f, dd = 0.f;
        #pragma unroll
        for (int g = 0; g < 4; ++g) {
            const float* pa = &part_a[g][t][0];
            n0 += pa[0]; n1 += pa[1]; n2 += pa[2]; n3 += pa[3]; dd += pa[4];
        }
        const float inv = 1.0f / dd;
        attn_c[h*4+0][r] = n0 * inv; attn_c[h*4+1][r] = n1 * inv;
        attn_c[h*4+2][r] = n2 * inv; attn_c[h*4+3][r] = n3 * inv;
    }
    __syncthreads();

    // ---- P4: out_proj -> LN1 -> zf ----
    if (t < QPB) {
        float av[NE];
        #pragma unroll
        for (int e = 0; e < NE; ++e) av[e] = attn_c[e][t];
        float y[NE];
        #pragma unroll
        for (int e = 0; e < NE; ++e) {
            float acc = 0.f;
            #pragma unroll
            for (int k = 0; k < NE; ++k) acc += av[k] * wout_s[e][k];
            y[e] = acc;
        }
        const float* xr = x + ((size_t)b * NS + qc * QPB + t) * NE;
        const float4 xv0 = *reinterpret_cast<const float4*>(xr);
        const float4 xv1 = *reinterpret_cast<const float4*>(xr + 4);
        float t1[NE];
        t1[0] = xv0.x + y[0]; t1[1] = xv0.y + y[1]; t1[2] = xv0.z + y[2]; t1[3] = xv0.w + y[3];
        t1[4] = xv1.x + y[4]; t1[5] = xv1.y + y[5]; t1[6] = xv1.z + y[6]; t1[7] = xv1.w + y[7];
        float mu = 0.f;
        #pragma unroll
        for (int e = 0; e < NE; ++e) mu += t1[e];
        mu *= 0.125f;
        float var = 0.f;
        #pragma unroll
        for (int e = 0; e < NE; ++e) { const float d = t1[e] - mu; var += d * d; }
        var *= 0.125f;
        const float inv1 = rsqrtf(var + LNEPS);
        #pragma unroll
        for (int e = 0; e < NE; ++e) {
            const float x1e = (t1[e] - mu) * inv1 * g1_s[e] + be1_s[e];
            x1_c[e][t] = x1e;
            zf_c[e][t] = cry_s[e] * __cosf(x1e);
        }
    }
    __syncthreads();

    // ---- P5: FFN, lane = row, wave-uniform weight broadcasts ----
    {
        const int w = t >> 6, fs = w >> 1;
        const int row = (w & 1) * 64 + (t & 63);
        f32x2 zf01 = {zf_c[0][row], zf_c[1][row]};
        f32x2 zf23 = {zf_c[2][row], zf_c[3][row]};
        f32x2 zf45 = {zf_c[4][row], zf_c[5][row]};
        f32x2 zf67 = {zf_c[6][row], zf_c[7][row]};
        f32x2 acc01 = {0.f,0.f}, acc23 = {0.f,0.f}, acc45 = {0.f,0.f}, acc67 = {0.f,0.f};
        #pragma unroll 4
        for (int i = 0; i < 64; ++i) {
            const int f = fs * 64 + i;
            const float4 wa = *reinterpret_cast<const float4*>(&w1_s[f][0]);
            const float4 wb = *reinterpret_cast<const float4*>(&w1_s[f][4]);
            const f32x2 ha = zf01 * (f32x2){wa.x, wa.y} + zf23 * (f32x2){wa.z, wa.w};
            const f32x2 hb = zf45 * (f32x2){wb.x, wb.y} + zf67 * (f32x2){wb.z, wb.w};
            float hv = b1_s[f] + ha.x + ha.y + hb.x + hb.y;
            hv = fmaxf(hv, 0.f);
            const float4 ua = *reinterpret_cast<const float4*>(&w2t_s[f][0]);
            const float4 ub = *reinterpret_cast<const float4*>(&w2t_s[f][4]);
            acc01 += hv * (f32x2){ua.x, ua.y};
            acc23 += hv * (f32x2){ua.z, ua.w};
            acc45 += hv * (f32x2){ub.x, ub.y};
            acc67 += hv * (f32x2){ub.z, ub.w};
        }
        part_f[fs][0][row] = acc01.x; part_f[fs][1][row] = acc01.y;
        part_f[fs][2][row] = acc23.x; part_f[fs][3][row] = acc23.y;
        part_f[fs][4][row] = acc45.x; part_f[fs][5][row] = acc45.y;
        part_f[fs][6][row] = acc67.x; part_f[fs][7][row] = acc67.y;
    }
    __syncthreads();

    // ---- P6a: reduce f-splits, add residual + b2 ----
    {
        const int e = t >> 7, r = t & 127;
        float s = 0.f;
        #pragma unroll
        for (int fs = 0; fs < 8; ++fs) s += part_f[fs][e][r];
        zf_c[e][r] = x1_c[e][r] + s + b2_s[e];   // reuse zf_c as t2
    }
    __syncthreads();

    // ---- P6b: LN2 + store ----
    if (t < QPB) {
        float t2[NE];
        #pragma unroll
        for (int e = 0; e < NE; ++e) t2[e] = zf_c[e][t];
        float mu = 0.f;
        #pragma unroll
        for (int e = 0; e < NE; ++e) mu += t2[e];
        mu *= 0.125f;
        float var = 0.f;
        #pragma unroll
        for (int e = 0; e < NE; ++e) { const float d = t2[e] - mu; var += d * d; }
        var *= 0.125f;
        const float inv2 = rsqrtf(var + LNEPS);
        float o[NE];
        #pragma unroll
        for (int e = 0; e < NE; ++e) o[e] = (t2[e] - mu) * inv2 * g2_s[e] + be2_s[e];
        float4* o4 = reinterpret_cast<float4*>(out + ((size_t)b * NS + qc * QPB + t) * NE);
        o4[0] = make_float4(o[0], o[1], o[2], o[3]);
        o4[1] = make_float4(o[4], o[5], o[6], o[7]);
    }
}

extern "C" void kernel_launch(void* const* d_in, const int* in_sizes, int n_in,
                              void* d_out, int out_size, void* d_ws, size_t ws_size,
                              hipStream_t stream) {
    const float* x        = (const float*)d_in[0];
    const float* theta_rx = (const float*)d_in[1];
    const float* w_out    = (const float*)d_in[2];
    const float* theta_ry = (const float*)d_in[3];
    const float* w1       = (const float*)d_in[4];
    const float* b1       = (const float*)d_in[5];
    const float* w2       = (const float*)d_in[6];
    const float* b2       = (const float*)d_in[7];
    const float* g1       = (const float*)d_in[8];
    const float* be1      = (const float*)d_in[9];
    const float* g2       = (const float*)d_in[10];
    const float* be2      = (const float*)d_in[11];
    float* out = (float*)d_out;
    float* ws  = (float*)d_ws;

    k1_moments<<<dim3(NB * NH * 32), dim3(256), 0, stream>>>(x, theta_rx, ws);
    k15_reduce<<<dim3(32), dim3(256), 0, stream>>>(ws);
    k2_main<<<dim3(NB * (NS / QPB)), dim3(1024), 0, stream>>>(
        x, theta_rx, w_out, theta_ry, w1, b1, w2, b2, g1, be1, g2, be2, ws, out);
}